// Round 11
// baseline (185.578 us; speedup 1.0000x reference)
//
#include <hip/hip_runtime.h>

#define N_NODES   50000
#define N_EDGES   600000
#define F_IN      128
#define H_DIM     256
#define N_CLASSES 16
#define N_GRAPHS  64
#define M_PAD     50048   // 782 * 64
#define MAX_DEG   64      // Poisson(12): P(deg>40) ~ 1e-10
#define ZERO_WORDS (50000 + 1024 + 64 + 1)

typedef unsigned short ushort_t;
typedef unsigned int   uint_t;
typedef __attribute__((ext_vector_type(8))) short bf16x8;
typedef __attribute__((ext_vector_type(4))) float f32x4;

__device__ inline ushort_t f2bf(float f) {
    union { float f; uint_t u; } v; v.f = f;
    uint_t r = v.u + 0x7FFF + ((v.u >> 16) & 1);
    return (ushort_t)(r >> 16);
}
__device__ inline float bf2f(uint_t u) {
    union { uint_t u; float f; } v; v.u = u << 16;
    return v.f;
}
__device__ inline void load_lds16(const void* g, void* l) {
    __builtin_amdgcn_global_load_lds(
        (const __attribute__((address_space(1))) void*)g,
        (__attribute__((address_space(3))) void*)l, 16, 0, 0);
}
__device__ inline void acc8(float* a, uint4 v) {
    a[0] += bf2f(v.x & 0xFFFFu); a[1] += bf2f(v.x >> 16);
    a[2] += bf2f(v.y & 0xFFFFu); a[3] += bf2f(v.y >> 16);
    a[4] += bf2f(v.z & 0xFFFFu); a[5] += bf2f(v.z >> 16);
    a[6] += bf2f(v.w & 0xFFFFu); a[7] += bf2f(v.w >> 16);
}

// ---------------------------------------------------------------------------
// prep: zero cnt/gsum/gcnt/done; ha[n][128..255]=bf16(x[n]); Bt/Bt2 transpose
__global__ __launch_bounds__(256) void prep_kernel(
    const float* __restrict__ x,
    const float* __restrict__ W1l, const float* __restrict__ W1r,
    const float* __restrict__ W2l, const float* __restrict__ W2r,
    uint_t* __restrict__ wszero, ushort_t* __restrict__ ha,
    ushort_t* __restrict__ Bt, ushort_t* __restrict__ Bt2) {
    const int t = blockIdx.x * blockDim.x + threadIdx.x;
    if (t < ZERO_WORDS) wszero[t] = 0u;
    if (t < 65536) {
        const int n = t >> 8, k = t & 255;
        const float v = (k < 128) ? W1l[k * H_DIM + n] : W1r[(k - 128) * H_DIM + n];
        Bt[n * 256 + k] = f2bf(v);
    } else if (t < 65536 + 8192) {
        const int t2 = t - 65536;
        const int c = t2 >> 8, k = t2 & 255;
        const float v = (c < 16) ? W2l[k * N_CLASSES + c] : W2r[k * N_CLASSES + (c - 16)];
        Bt2[c * 256 + k] = f2bf(v);
    }
    if (t >= N_NODES * 32) return;
    const int n = t >> 5, c = t & 31;
    const float4 v = *reinterpret_cast<const float4*>(x + (size_t)n * F_IN + c * 4);
    uint2 pk;
    pk.x = (uint_t)f2bf(v.x) | ((uint_t)f2bf(v.y) << 16);
    pk.y = (uint_t)f2bf(v.z) | ((uint_t)f2bf(v.w) << 16);
    *reinterpret_cast<uint2*>(ha + (size_t)n * 256 + 128 + c * 4) = pk;
}

// scatter_pad: slots[dst*64 + pos++] = src
__global__ void scatter_pad_kernel(const int* __restrict__ src,
                                   const int* __restrict__ dst,
                                   int* __restrict__ cnt,
                                   int* __restrict__ slots) {
    int e = blockIdx.x * blockDim.x + threadIdx.x;
    if (e >= N_EDGES) return;
    const int d = dst[e];
    const int pos = atomicAdd(&cnt[d], 1);
    if (pos < MAX_DEG) slots[d * MAX_DEG + pos] = src[e];
}

// ---------------------------------------------------------------------------
// agg1: wave per node; 16 edge slots x 4 lanes x 64B (4 x uint4) each.
// 16 edges concurrently (vs 8 in R7) -> deg<=16 gathered in ONE round.
__global__ __launch_bounds__(256) void agg1_kernel(const int* __restrict__ cnt,
                                                   const int* __restrict__ slots,
                                                   ushort_t* __restrict__ ha,
                                                   float* __restrict__ invdeg) {
    const int n = blockIdx.x * 4 + (threadIdx.x >> 6);
    if (n >= N_NODES) return;
    const int lane = threadIdx.x & 63;
    const int slot = lane >> 2;         // 0..15: edge slot
    const int c    = lane & 3;          // 64B quarter of the 256B bf16 row
    const int deg  = min(cnt[n], MAX_DEG);
    const int* srow = slots + n * MAX_DEG;
    float a[32];
#pragma unroll
    for (int i = 0; i < 32; ++i) a[i] = 0.f;
    for (int e = slot; e < deg; e += 16) {
        const int s = srow[e];
        const ushort_t* rp = ha + (size_t)s * 256 + 128 + c * 32;
        const uint4 w0 = *reinterpret_cast<const uint4*>(rp);
        const uint4 w1 = *reinterpret_cast<const uint4*>(rp + 8);
        const uint4 w2 = *reinterpret_cast<const uint4*>(rp + 16);
        const uint4 w3 = *reinterpret_cast<const uint4*>(rp + 24);
        acc8(a +  0, w0);
        acc8(a +  8, w1);
        acc8(a + 16, w2);
        acc8(a + 24, w3);
    }
#pragma unroll
    for (int i = 0; i < 32; ++i) {
        a[i] += __shfl_xor(a[i], 4);
        a[i] += __shfl_xor(a[i], 8);
        a[i] += __shfl_xor(a[i], 16);
        a[i] += __shfl_xor(a[i], 32);
    }
    const float iv = 1.0f / fmaxf((float)deg, 1.0f);
    if (slot == 0) {
        uint_t pk[16];
#pragma unroll
        for (int j = 0; j < 16; ++j)
            pk[j] = (uint_t)f2bf(a[2 * j] * iv) | ((uint_t)f2bf(a[2 * j + 1] * iv) << 16);
        ushort_t* orow = ha + (size_t)n * 256 + c * 32;
        *reinterpret_cast<uint4*>(orow)      = (uint4){pk[0],  pk[1],  pk[2],  pk[3]};
        *reinterpret_cast<uint4*>(orow + 8)  = (uint4){pk[4],  pk[5],  pk[6],  pk[7]};
        *reinterpret_cast<uint4*>(orow + 16) = (uint4){pk[8],  pk[9],  pk[10], pk[11]};
        *reinterpret_cast<uint4*>(orow + 24) = (uint4){pk[12], pk[13], pk[14], pk[15]};
        if (c == 0) invdeg[n] = iv;
    }
}

// ---------------------------------------------------------------------------
// gemm1_fused (R7 proven: sA 32K + sB 16K single-buffer, 3 blocks/CU);
// h = relu(ha @ Bt^T + b1); then p|r = h @ [W2l|W2r]; p,r stored fp32.
__global__ __launch_bounds__(256) void gemm1_fused_kernel(
    const ushort_t* __restrict__ ha, const ushort_t* __restrict__ Bt,
    const ushort_t* __restrict__ Bt2, const float* __restrict__ b1,
    float* __restrict__ p, float* __restrict__ r) {
    __shared__ ushort_t sA[64 * 256];   // 32 KiB, rows stride 512B, swizzled
    __shared__ ushort_t sB[32 * 256];   // 16 KiB: one phase of 32 n-rows
    const int tid  = threadIdx.x;
    const int mblk = blockIdx.x;

    const char* gA = (const char*)ha + (size_t)mblk * 32768;
    const char* gB = (const char*)Bt;
#pragma unroll
    for (int i = 0; i < 8; ++i) {
        const int d = (i * 256 + tid) * 16;
        const int s = d ^ (((d >> 9) & 7) << 4);
        load_lds16(gA + s, (char*)sA + (d & ~1023));
    }
#pragma unroll
    for (int i = 0; i < 4; ++i) {
        const int d = (i * 256 + tid) * 16;
        const int s = d ^ (((d >> 9) & 7) << 4);
        load_lds16(gB + s, (char*)sB + (d & ~1023));
    }
    __syncthreads();

    const int w    = tid >> 6;
    const int lane = tid & 63;
    const int lr   = lane & 15;
    const int hi   = lane >> 4;
    const int m0   = w * 16;

    bf16x8 afr[8];
    {
        const int row = m0 + lr;
        const int sw = (row & 7) << 4;
#pragma unroll
        for (int ks = 0; ks < 8; ++ks)
            afr[ks] = *reinterpret_cast<const bf16x8*>(
                (const char*)sA + ((row * 512 + ks * 64 + hi * 16) ^ sw));
    }

    f32x4 acc[16];
#pragma unroll
    for (int t = 0; t < 16; ++t) acc[t] = (f32x4){0.f, 0.f, 0.f, 0.f};

#pragma unroll
    for (int ph = 0; ph < 8; ++ph) {
#pragma unroll
        for (int fnl = 0; fnl < 2; ++fnl) {
            const int rn = fnl * 16 + lr;
            const int sw = (rn & 7) << 4;
#pragma unroll
            for (int ks = 0; ks < 8; ++ks) {
                const bf16x8 bfr = *reinterpret_cast<const bf16x8*>(
                    (const char*)sB + ((rn * 512 + ks * 64 + hi * 16) ^ sw));
                acc[ph * 2 + fnl] = __builtin_amdgcn_mfma_f32_16x16x32_bf16(
                    afr[ks], bfr, acc[ph * 2 + fnl], 0, 0, 0);
            }
        }
        __syncthreads();
        if (ph < 7) {
#pragma unroll
            for (int i = 0; i < 4; ++i) {
                const int d = (i * 256 + tid) * 16;
                const int s = d ^ (((d >> 9) & 7) << 4);
                load_lds16(gB + (ph + 1) * 16384 + s, (char*)sB + (d & ~1023));
            }
            __syncthreads();
        }
    }

    // epilogue: h = relu(acc + b1) -> bf16 into sA (dead), swizzled
#pragma unroll
    for (int t = 0; t < 16; ++t) {
        const int colG = t * 16 + lr;
        const float bias = b1[colG];
#pragma unroll
        for (int i = 0; i < 4; ++i) {
            const int row = m0 + hi * 4 + i;
            const float h = fmaxf(acc[t][i] + bias, 0.f);
            const int ad = (row * 512 + colG * 2) ^ ((row & 7) << 4);
            *reinterpret_cast<ushort_t*>((char*)sA + ad) = f2bf(h);
        }
    }
    __syncthreads();

    // stage 2: p|r = h @ [W2l|W2r] ; wave handles its 16 node-rows
    const char* bt2b = (const char*)Bt2;
    const int nr = m0 + lr;
    const int swn = (nr & 7) << 4;
    f32x4 acc2[2] = {(f32x4){0.f, 0.f, 0.f, 0.f}, (f32x4){0.f, 0.f, 0.f, 0.f}};
#pragma unroll
    for (int fc = 0; fc < 2; ++fc) {
#pragma unroll
        for (int k2 = 0; k2 < 8; ++k2) {
            const bf16x8 a2 = *reinterpret_cast<const bf16x8*>(
                bt2b + (fc * 16 + lr) * 512 + k2 * 64 + hi * 16);
            const bf16x8 b2 = *reinterpret_cast<const bf16x8*>(
                (const char*)sA + ((nr * 512 + k2 * 64 + hi * 16) ^ swn));
            acc2[fc] = __builtin_amdgcn_mfma_f32_16x16x32_bf16(a2, b2, acc2[fc], 0, 0, 0);
        }
    }

    const int node = mblk * 64 + nr;
    if (node < N_NODES) {
#pragma unroll
        for (int i = 0; i < 4; ++i) {
            p[(size_t)node * N_CLASSES + hi * 4 + i] = acc2[0][i];
            r[(size_t)node * N_CLASSES + hi * 4 + i] = acc2[1][i];
        }
    }
}

// ---------------------------------------------------------------------------
// agg2 (R7 proven): wave per node, 16 edge slots x 4 lanes x float4
__global__ __launch_bounds__(256) void agg2_kernel(const float* __restrict__ p,
                                                   const int* __restrict__ cnt,
                                                   const int* __restrict__ slots,
                                                   float* __restrict__ psum) {
    const int n = blockIdx.x * 4 + (threadIdx.x >> 6);
    if (n >= N_NODES) return;
    const int lane = threadIdx.x & 63;
    const int slot = lane >> 2;        // 0..15: edge slot
    const int c    = lane & 3;         // float4 chunk
    const int deg  = min(cnt[n], MAX_DEG);
    const int* srow = slots + n * MAX_DEG;
    float4 acc = {0.f, 0.f, 0.f, 0.f};
    for (int e = slot; e < deg; e += 16) {
        const int s = srow[e];
        const float4 v = *reinterpret_cast<const float4*>(p + (size_t)s * N_CLASSES + c * 4);
        acc.x += v.x; acc.y += v.y; acc.z += v.z; acc.w += v.w;
    }
#pragma unroll
    for (int o = 4; o < 64; o <<= 1) {
        acc.x += __shfl_xor(acc.x, o);
        acc.y += __shfl_xor(acc.y, o);
        acc.z += __shfl_xor(acc.z, o);
        acc.w += __shfl_xor(acc.w, o);
    }
    if (slot == 0)
        *reinterpret_cast<float4*>(psum + (size_t)n * N_CLASSES + c * 4) = acc;
}

// ---------------------------------------------------------------------------
// pool_lsm (R7 proven, 782 blocks): h2 = relu(psum*invdeg + r + b2) ->
// LDS graph sums -> global atomics; LAST block computes log_softmax.
__global__ __launch_bounds__(256) void pool_lsm_kernel(
    const float* __restrict__ psum, const float* __restrict__ r,
    const float* __restrict__ invdeg, const float* __restrict__ b2,
    const int* __restrict__ batch,
    float* __restrict__ gsum, float* __restrict__ gcnt,
    int* __restrict__ done, float* __restrict__ out, int nblocks) {
    __shared__ float lgsum[N_GRAPHS * N_CLASSES];
    __shared__ float lgcnt[N_GRAPHS];
    __shared__ int gminmax[2];
    __shared__ int last;
    const int t = threadIdx.x;
    const int base = blockIdx.x * 64;
#pragma unroll
    for (int k = 0; k < 4; ++k) lgsum[t + 256 * k] = 0.f;
    if (t < N_GRAPHS) lgcnt[t] = 0.f;
    if (t == 0) {
        gminmax[0] = batch[base];
        int lastn = base + 63; if (lastn >= N_NODES) lastn = N_NODES - 1;
        gminmax[1] = batch[lastn];
    }
    __syncthreads();

    const int j = t & 15;
    const float bj = b2[j];
#pragma unroll
    for (int k = 0; k < 4; ++k) {
        const int i = base + (t >> 4) + 16 * k;
        if (i < N_NODES) {
            float h = psum[(size_t)i * N_CLASSES + j] * invdeg[i]
                      + r[(size_t)i * N_CLASSES + j] + bj;
            h = fmaxf(h, 0.f);
            const int g = batch[i];
            atomicAdd(&lgsum[g * N_CLASSES + j], h);
            if (j == 0) atomicAdd(&lgcnt[g], 1.0f);
        }
    }
    __syncthreads();

    const int gmin = gminmax[0], gmax = gminmax[1];
    for (int gg = gmin + (t >> 4); gg <= gmax; gg += 16) {
        const float v = lgsum[gg * N_CLASSES + j];
        if (v != 0.f) atomicAdd(&gsum[gg * N_CLASSES + j], v);
    }
    if (t < N_GRAPHS) {
        const int gg = gmin + t;
        if (gg <= gmax) {
            const float c = lgcnt[gg];
            if (c != 0.f) atomicAdd(&gcnt[gg], c);
        }
    }
    __syncthreads();

    if (t == 0) {
        __threadfence();
        const int old = __hip_atomic_fetch_add(done, 1, __ATOMIC_ACQ_REL,
                                               __HIP_MEMORY_SCOPE_AGENT);
        last = (old == nblocks - 1) ? 1 : 0;
    }
    __syncthreads();

    if (last && t < N_GRAPHS) {
        const int g = t;
        const float cg = __hip_atomic_load(&gcnt[g], __ATOMIC_RELAXED,
                                           __HIP_MEMORY_SCOPE_AGENT);
        const float iv = 1.0f / fmaxf(cg, 1.0f);
        float v[N_CLASSES];
        float m = -1e30f;
#pragma unroll
        for (int jj = 0; jj < N_CLASSES; ++jj) {
            v[jj] = __hip_atomic_load(&gsum[g * N_CLASSES + jj], __ATOMIC_RELAXED,
                                      __HIP_MEMORY_SCOPE_AGENT) * iv;
            m = fmaxf(m, v[jj]);
        }
        float s = 0.f;
#pragma unroll
        for (int jj = 0; jj < N_CLASSES; ++jj) s += expf(v[jj] - m);
        const float lse = logf(s);
#pragma unroll
        for (int jj = 0; jj < N_CLASSES; ++jj)
            out[g * N_CLASSES + jj] = v[jj] - m - lse;
    }
}

// ---------------------------------------------------------------------------
extern "C" void kernel_launch(void* const* d_in, const int* in_sizes, int n_in,
                              void* d_out, int out_size, void* d_ws, size_t ws_size,
                              hipStream_t stream) {
    const float* x    = (const float*)d_in[0];
    const int*   ei   = (const int*)d_in[1];
    const int*   batch= (const int*)d_in[2];
    const float* W1l  = (const float*)d_in[3];
    const float* W1r  = (const float*)d_in[4];
    const float* b1   = (const float*)d_in[5];
    const float* W2l  = (const float*)d_in[6];
    const float* W2r  = (const float*)d_in[7];
    const float* b2   = (const float*)d_in[8];
    float* out = (float*)d_out;

    const int* src = ei;
    const int* dst = ei + N_EDGES;

    // workspace layout (4-byte words); zero region first
    float* ws     = (float*)d_ws;
    int*   cnt    = (int*)ws;                           //    50,000
    float* gsum   = ws + 50000;                         //     1,024
    float* gcnt   = gsum + 1024;                        //        64
    int*   done   = (int*)(gcnt + 64);                  //         1
    float* invdeg = (float*)(done + 1);                 //    50,000
    int*   slots  = (int*)(invdeg + 50000);             // 3,200,000
    ushort_t* Bt  = (ushort_t*)(slots + 3200000 + 3);   //    65,536 ushort (16B align)
    ushort_t* Bt2 = Bt + 65536;                         //     8,192 ushort
    ushort_t* ha  = Bt2 + 8192;                         // M_PAD*256 ushort
    float* p      = (float*)(ha + (size_t)M_PAD * 256); // M_PAD*16 float
    float* r      = p + (size_t)M_PAD * 16;             // M_PAD*16 float
    float* psum   = (float*)ha;                         // alias: ha dead after gemm1

    const int PB = 782;  // pool blocks
    prep_kernel<<<(N_NODES * 32 + 255) / 256, 256, 0, stream>>>(
        x, W1l, W1r, W2l, W2r, (uint_t*)ws, ha, Bt, Bt2);
    scatter_pad_kernel<<<(N_EDGES + 255) / 256, 256, 0, stream>>>(src, dst, cnt, slots);
    agg1_kernel<<<(N_NODES + 3) / 4, 256, 0, stream>>>(cnt, slots, ha, invdeg);
    gemm1_fused_kernel<<<M_PAD / 64, 256, 0, stream>>>(ha, Bt, Bt2, b1, p, r);
    agg2_kernel<<<(N_NODES + 3) / 4, 256, 0, stream>>>(p, cnt, slots, psum);
    pool_lsm_kernel<<<PB, 256, 0, stream>>>(psum, r, invdeg, b2, batch,
                                            gsum, gcnt, done, out, PB);
}

// Round 12
// 150.006 us; speedup vs baseline: 1.2371x; 1.2371x over previous
//
#include <hip/hip_runtime.h>

#define N_NODES   50000
#define N_EDGES   600000
#define F_IN      128
#define H_DIM     256
#define N_CLASSES 16
#define N_GRAPHS  64
#define M_PAD     50048   // 782 * 64
#define MAX_DEG   64      // Poisson(12): P(deg>40) ~ 1e-10
#define ZERO_WORDS (50000 + 1024 + 64 + 1)

typedef unsigned short ushort_t;
typedef unsigned int   uint_t;
typedef __attribute__((ext_vector_type(8))) short bf16x8;
typedef __attribute__((ext_vector_type(4))) float f32x4;

__device__ inline ushort_t f2bf(float f) {
    union { float f; uint_t u; } v; v.f = f;
    uint_t r = v.u + 0x7FFF + ((v.u >> 16) & 1);
    return (ushort_t)(r >> 16);
}
__device__ inline float bf2f(uint_t u) {
    union { uint_t u; float f; } v; v.u = u << 16;
    return v.f;
}
__device__ inline void load_lds16(const void* g, void* l) {
    __builtin_amdgcn_global_load_lds(
        (const __attribute__((address_space(1))) void*)g,
        (__attribute__((address_space(3))) void*)l, 16, 0, 0);
}

// ---------------------------------------------------------------------------
// prep: zero cnt/gsum/gcnt/done; ha[n][128..255]=bf16(x[n]); Bt/Bt2 transpose
__global__ __launch_bounds__(256) void prep_kernel(
    const float* __restrict__ x,
    const float* __restrict__ W1l, const float* __restrict__ W1r,
    const float* __restrict__ W2l, const float* __restrict__ W2r,
    uint_t* __restrict__ wszero, ushort_t* __restrict__ ha,
    ushort_t* __restrict__ Bt, ushort_t* __restrict__ Bt2) {
    const int t = blockIdx.x * blockDim.x + threadIdx.x;
    if (t < ZERO_WORDS) wszero[t] = 0u;
    if (t < 65536) {
        const int n = t >> 8, k = t & 255;
        const float v = (k < 128) ? W1l[k * H_DIM + n] : W1r[(k - 128) * H_DIM + n];
        Bt[n * 256 + k] = f2bf(v);
    } else if (t < 65536 + 8192) {
        const int t2 = t - 65536;
        const int c = t2 >> 8, k = t2 & 255;
        const float v = (c < 16) ? W2l[k * N_CLASSES + c] : W2r[k * N_CLASSES + (c - 16)];
        Bt2[c * 256 + k] = f2bf(v);
    }
    if (t >= N_NODES * 32) return;
    const int n = t >> 5, c = t & 31;
    const float4 v = *reinterpret_cast<const float4*>(x + (size_t)n * F_IN + c * 4);
    uint2 pk;
    pk.x = (uint_t)f2bf(v.x) | ((uint_t)f2bf(v.y) << 16);
    pk.y = (uint_t)f2bf(v.z) | ((uint_t)f2bf(v.w) << 16);
    *reinterpret_cast<uint2*>(ha + (size_t)n * 256 + 128 + c * 4) = pk;
}

// scatter_pad: slots[dst*64 + pos++] = src
__global__ void scatter_pad_kernel(const int* __restrict__ src,
                                   const int* __restrict__ dst,
                                   int* __restrict__ cnt,
                                   int* __restrict__ slots) {
    int e = blockIdx.x * blockDim.x + threadIdx.x;
    if (e >= N_EDGES) return;
    const int d = dst[e];
    const int pos = atomicAdd(&cnt[d], 1);
    if (pos < MAX_DEG) slots[d * MAX_DEG + pos] = src[e];
}

// ---------------------------------------------------------------------------
// agg1: wave per node, padded slots, 2-deep pipelined gather (R7 proven)
__global__ __launch_bounds__(256) void agg1_kernel(const int* __restrict__ cnt,
                                                   const int* __restrict__ slots,
                                                   ushort_t* __restrict__ ha,
                                                   float* __restrict__ invdeg) {
    const int n = blockIdx.x * 4 + (threadIdx.x >> 6);
    if (n >= N_NODES) return;
    const int lane = threadIdx.x & 63;
    const int slot = lane >> 3;         // 0..7
    const int c    = lane & 7;          // 16B chunk within 128B half
    const int deg  = min(cnt[n], MAX_DEG);
    const int* srow = slots + n * MAX_DEG;
    float a[16];
#pragma unroll
    for (int i = 0; i < 16; ++i) a[i] = 0.f;
    for (int e = slot; e < deg; e += 16) {
        const int s0 = srow[e];
        const ushort_t* r0 = ha + (size_t)s0 * 256 + 128;
        const uint4 v00 = *reinterpret_cast<const uint4*>(r0 + c * 8);
        const uint4 v01 = *reinterpret_cast<const uint4*>(r0 + 64 + c * 8);
        const int e1 = e + 8;
        uint4 v10, v11;
        if (e1 < deg) {
            const int s1 = srow[e1];
            const ushort_t* r1 = ha + (size_t)s1 * 256 + 128;
            v10 = *reinterpret_cast<const uint4*>(r1 + c * 8);
            v11 = *reinterpret_cast<const uint4*>(r1 + 64 + c * 8);
        }
        a[0] += bf2f(v00.x & 0xFFFFu); a[1] += bf2f(v00.x >> 16);
        a[2] += bf2f(v00.y & 0xFFFFu); a[3] += bf2f(v00.y >> 16);
        a[4] += bf2f(v00.z & 0xFFFFu); a[5] += bf2f(v00.z >> 16);
        a[6] += bf2f(v00.w & 0xFFFFu); a[7] += bf2f(v00.w >> 16);
        a[8]  += bf2f(v01.x & 0xFFFFu); a[9]  += bf2f(v01.x >> 16);
        a[10] += bf2f(v01.y & 0xFFFFu); a[11] += bf2f(v01.y >> 16);
        a[12] += bf2f(v01.z & 0xFFFFu); a[13] += bf2f(v01.z >> 16);
        a[14] += bf2f(v01.w & 0xFFFFu); a[15] += bf2f(v01.w >> 16);
        if (e1 < deg) {
            a[0] += bf2f(v10.x & 0xFFFFu); a[1] += bf2f(v10.x >> 16);
            a[2] += bf2f(v10.y & 0xFFFFu); a[3] += bf2f(v10.y >> 16);
            a[4] += bf2f(v10.z & 0xFFFFu); a[5] += bf2f(v10.z >> 16);
            a[6] += bf2f(v10.w & 0xFFFFu); a[7] += bf2f(v10.w >> 16);
            a[8]  += bf2f(v11.x & 0xFFFFu); a[9]  += bf2f(v11.x >> 16);
            a[10] += bf2f(v11.y & 0xFFFFu); a[11] += bf2f(v11.y >> 16);
            a[12] += bf2f(v11.z & 0xFFFFu); a[13] += bf2f(v11.z >> 16);
            a[14] += bf2f(v11.w & 0xFFFFu); a[15] += bf2f(v11.w >> 16);
        }
    }
#pragma unroll
    for (int i = 0; i < 16; ++i) {
        a[i] += __shfl_xor(a[i], 8);
        a[i] += __shfl_xor(a[i], 16);
        a[i] += __shfl_xor(a[i], 32);
    }
    const float iv = 1.0f / fmaxf((float)deg, 1.0f);
    if (slot == 0) {
        uint4 pk0, pk1;
        pk0.x = (uint_t)f2bf(a[0] * iv) | ((uint_t)f2bf(a[1] * iv) << 16);
        pk0.y = (uint_t)f2bf(a[2] * iv) | ((uint_t)f2bf(a[3] * iv) << 16);
        pk0.z = (uint_t)f2bf(a[4] * iv) | ((uint_t)f2bf(a[5] * iv) << 16);
        pk0.w = (uint_t)f2bf(a[6] * iv) | ((uint_t)f2bf(a[7] * iv) << 16);
        pk1.x = (uint_t)f2bf(a[8]  * iv) | ((uint_t)f2bf(a[9]  * iv) << 16);
        pk1.y = (uint_t)f2bf(a[10] * iv) | ((uint_t)f2bf(a[11] * iv) << 16);
        pk1.z = (uint_t)f2bf(a[12] * iv) | ((uint_t)f2bf(a[13] * iv) << 16);
        pk1.w = (uint_t)f2bf(a[14] * iv) | ((uint_t)f2bf(a[15] * iv) << 16);
        ushort_t* orow = ha + (size_t)n * 256;
        *reinterpret_cast<uint4*>(orow + c * 8) = pk0;
        *reinterpret_cast<uint4*>(orow + 64 + c * 8) = pk1;
        if (c == 0) invdeg[n] = iv;
    }
}

// ---------------------------------------------------------------------------
// gemm1_fused (R7 proven: sA 32K + sB 16K single-buffer, 3 blocks/CU);
// h = relu(ha @ Bt^T + b1); then p|r = h @ [W2l|W2r]; p,r stored fp32.
__global__ __launch_bounds__(256) void gemm1_fused_kernel(
    const ushort_t* __restrict__ ha, const ushort_t* __restrict__ Bt,
    const ushort_t* __restrict__ Bt2, const float* __restrict__ b1,
    float* __restrict__ p, float* __restrict__ r) {
    __shared__ ushort_t sA[64 * 256];   // 32 KiB, rows stride 512B, swizzled
    __shared__ ushort_t sB[32 * 256];   // 16 KiB: one phase of 32 n-rows
    const int tid  = threadIdx.x;
    const int mblk = blockIdx.x;

    const char* gA = (const char*)ha + (size_t)mblk * 32768;
    const char* gB = (const char*)Bt;
#pragma unroll
    for (int i = 0; i < 8; ++i) {
        const int d = (i * 256 + tid) * 16;
        const int s = d ^ (((d >> 9) & 7) << 4);
        load_lds16(gA + s, (char*)sA + (d & ~1023));
    }
#pragma unroll
    for (int i = 0; i < 4; ++i) {
        const int d = (i * 256 + tid) * 16;
        const int s = d ^ (((d >> 9) & 7) << 4);
        load_lds16(gB + s, (char*)sB + (d & ~1023));
    }
    __syncthreads();

    const int w    = tid >> 6;
    const int lane = tid & 63;
    const int lr   = lane & 15;
    const int hi   = lane >> 4;
    const int m0   = w * 16;

    bf16x8 afr[8];
    {
        const int row = m0 + lr;
        const int sw = (row & 7) << 4;
#pragma unroll
        for (int ks = 0; ks < 8; ++ks)
            afr[ks] = *reinterpret_cast<const bf16x8*>(
                (const char*)sA + ((row * 512 + ks * 64 + hi * 16) ^ sw));
    }

    f32x4 acc[16];
#pragma unroll
    for (int t = 0; t < 16; ++t) acc[t] = (f32x4){0.f, 0.f, 0.f, 0.f};

#pragma unroll
    for (int ph = 0; ph < 8; ++ph) {
#pragma unroll
        for (int fnl = 0; fnl < 2; ++fnl) {
            const int rn = fnl * 16 + lr;
            const int sw = (rn & 7) << 4;
#pragma unroll
            for (int ks = 0; ks < 8; ++ks) {
                const bf16x8 bfr = *reinterpret_cast<const bf16x8*>(
                    (const char*)sB + ((rn * 512 + ks * 64 + hi * 16) ^ sw));
                acc[ph * 2 + fnl] = __builtin_amdgcn_mfma_f32_16x16x32_bf16(
                    afr[ks], bfr, acc[ph * 2 + fnl], 0, 0, 0);
            }
        }
        __syncthreads();
        if (ph < 7) {
#pragma unroll
            for (int i = 0; i < 4; ++i) {
                const int d = (i * 256 + tid) * 16;
                const int s = d ^ (((d >> 9) & 7) << 4);
                load_lds16(gB + (ph + 1) * 16384 + s, (char*)sB + (d & ~1023));
            }
            __syncthreads();
        }
    }

    // epilogue: h = relu(acc + b1) -> bf16 into sA (dead), swizzled
#pragma unroll
    for (int t = 0; t < 16; ++t) {
        const int colG = t * 16 + lr;
        const float bias = b1[colG];
#pragma unroll
        for (int i = 0; i < 4; ++i) {
            const int row = m0 + hi * 4 + i;
            const float h = fmaxf(acc[t][i] + bias, 0.f);
            const int ad = (row * 512 + colG * 2) ^ ((row & 7) << 4);
            *reinterpret_cast<ushort_t*>((char*)sA + ad) = f2bf(h);
        }
    }
    __syncthreads();

    // stage 2: p|r = h @ [W2l|W2r] ; wave handles its 16 node-rows
    const char* bt2b = (const char*)Bt2;
    const int nr = m0 + lr;
    const int swn = (nr & 7) << 4;
    f32x4 acc2[2] = {(f32x4){0.f, 0.f, 0.f, 0.f}, (f32x4){0.f, 0.f, 0.f, 0.f}};
#pragma unroll
    for (int fc = 0; fc < 2; ++fc) {
#pragma unroll
        for (int k2 = 0; k2 < 8; ++k2) {
            const bf16x8 a2 = *reinterpret_cast<const bf16x8*>(
                bt2b + (fc * 16 + lr) * 512 + k2 * 64 + hi * 16);
            const bf16x8 b2 = *reinterpret_cast<const bf16x8*>(
                (const char*)sA + ((nr * 512 + k2 * 64 + hi * 16) ^ swn));
            acc2[fc] = __builtin_amdgcn_mfma_f32_16x16x32_bf16(a2, b2, acc2[fc], 0, 0, 0);
        }
    }

    const int node = mblk * 64 + nr;
    if (node < N_NODES) {
#pragma unroll
        for (int i = 0; i < 4; ++i) {
            p[(size_t)node * N_CLASSES + hi * 4 + i] = acc2[0][i];
            r[(size_t)node * N_CLASSES + hi * 4 + i] = acc2[1][i];
        }
    }
}

// ---------------------------------------------------------------------------
// agg2 (R7 proven): wave per node, 16 edge slots x 4 lanes x float4
__global__ __launch_bounds__(256) void agg2_kernel(const float* __restrict__ p,
                                                   const int* __restrict__ cnt,
                                                   const int* __restrict__ slots,
                                                   float* __restrict__ psum) {
    const int n = blockIdx.x * 4 + (threadIdx.x >> 6);
    if (n >= N_NODES) return;
    const int lane = threadIdx.x & 63;
    const int slot = lane >> 2;        // 0..15: edge slot
    const int c    = lane & 3;         // float4 chunk
    const int deg  = min(cnt[n], MAX_DEG);
    const int* srow = slots + n * MAX_DEG;
    float4 acc = {0.f, 0.f, 0.f, 0.f};
    for (int e = slot; e < deg; e += 16) {
        const int s = srow[e];
        const float4 v = *reinterpret_cast<const float4*>(p + (size_t)s * N_CLASSES + c * 4);
        acc.x += v.x; acc.y += v.y; acc.z += v.z; acc.w += v.w;
    }
#pragma unroll
    for (int o = 4; o < 64; o <<= 1) {
        acc.x += __shfl_xor(acc.x, o);
        acc.y += __shfl_xor(acc.y, o);
        acc.z += __shfl_xor(acc.z, o);
        acc.w += __shfl_xor(acc.w, o);
    }
    if (slot == 0)
        *reinterpret_cast<float4*>(psum + (size_t)n * N_CLASSES + c * 4) = acc;
}

// ---------------------------------------------------------------------------
// pool_lsm (R7 proven, 782 blocks): h2 = relu(psum*invdeg + r + b2) ->
// LDS graph sums -> global atomics; LAST block computes log_softmax.
__global__ __launch_bounds__(256) void pool_lsm_kernel(
    const float* __restrict__ psum, const float* __restrict__ r,
    const float* __restrict__ invdeg, const float* __restrict__ b2,
    const int* __restrict__ batch,
    float* __restrict__ gsum, float* __restrict__ gcnt,
    int* __restrict__ done, float* __restrict__ out, int nblocks) {
    __shared__ float lgsum[N_GRAPHS * N_CLASSES];
    __shared__ float lgcnt[N_GRAPHS];
    __shared__ int gminmax[2];
    __shared__ int last;
    const int t = threadIdx.x;
    const int base = blockIdx.x * 64;
#pragma unroll
    for (int k = 0; k < 4; ++k) lgsum[t + 256 * k] = 0.f;
    if (t < N_GRAPHS) lgcnt[t] = 0.f;
    if (t == 0) {
        gminmax[0] = batch[base];
        int lastn = base + 63; if (lastn >= N_NODES) lastn = N_NODES - 1;
        gminmax[1] = batch[lastn];
    }
    __syncthreads();

    const int j = t & 15;
    const float bj = b2[j];
#pragma unroll
    for (int k = 0; k < 4; ++k) {
        const int i = base + (t >> 4) + 16 * k;
        if (i < N_NODES) {
            float h = psum[(size_t)i * N_CLASSES + j] * invdeg[i]
                      + r[(size_t)i * N_CLASSES + j] + bj;
            h = fmaxf(h, 0.f);
            const int g = batch[i];
            atomicAdd(&lgsum[g * N_CLASSES + j], h);
            if (j == 0) atomicAdd(&lgcnt[g], 1.0f);
        }
    }
    __syncthreads();

    const int gmin = gminmax[0], gmax = gminmax[1];
    for (int gg = gmin + (t >> 4); gg <= gmax; gg += 16) {
        const float v = lgsum[gg * N_CLASSES + j];
        if (v != 0.f) atomicAdd(&gsum[gg * N_CLASSES + j], v);
    }
    if (t < N_GRAPHS) {
        const int gg = gmin + t;
        if (gg <= gmax) {
            const float c = lgcnt[gg];
            if (c != 0.f) atomicAdd(&gcnt[gg], c);
        }
    }
    __syncthreads();

    if (t == 0) {
        __threadfence();
        const int old = __hip_atomic_fetch_add(done, 1, __ATOMIC_ACQ_REL,
                                               __HIP_MEMORY_SCOPE_AGENT);
        last = (old == nblocks - 1) ? 1 : 0;
    }
    __syncthreads();

    if (last && t < N_GRAPHS) {
        const int g = t;
        const float cg = __hip_atomic_load(&gcnt[g], __ATOMIC_RELAXED,
                                           __HIP_MEMORY_SCOPE_AGENT);
        const float iv = 1.0f / fmaxf(cg, 1.0f);
        float v[N_CLASSES];
        float m = -1e30f;
#pragma unroll
        for (int jj = 0; jj < N_CLASSES; ++jj) {
            v[jj] = __hip_atomic_load(&gsum[g * N_CLASSES + jj], __ATOMIC_RELAXED,
                                      __HIP_MEMORY_SCOPE_AGENT) * iv;
            m = fmaxf(m, v[jj]);
        }
        float s = 0.f;
#pragma unroll
        for (int jj = 0; jj < N_CLASSES; ++jj) s += expf(v[jj] - m);
        const float lse = logf(s);
#pragma unroll
        for (int jj = 0; jj < N_CLASSES; ++jj)
            out[g * N_CLASSES + jj] = v[jj] - m - lse;
    }
}

// ---------------------------------------------------------------------------
extern "C" void kernel_launch(void* const* d_in, const int* in_sizes, int n_in,
                              void* d_out, int out_size, void* d_ws, size_t ws_size,
                              hipStream_t stream) {
    const float* x    = (const float*)d_in[0];
    const int*   ei   = (const int*)d_in[1];
    const int*   batch= (const int*)d_in[2];
    const float* W1l  = (const float*)d_in[3];
    const float* W1r  = (const float*)d_in[4];
    const float* b1   = (const float*)d_in[5];
    const float* W2l  = (const float*)d_in[6];
    const float* W2r  = (const float*)d_in[7];
    const float* b2   = (const float*)d_in[8];
    float* out = (float*)d_out;

    const int* src = ei;
    const int* dst = ei + N_EDGES;

    // workspace layout (4-byte words); zero region first
    float* ws     = (float*)d_ws;
    int*   cnt    = (int*)ws;                           //    50,000
    float* gsum   = ws + 50000;                         //     1,024
    float* gcnt   = gsum + 1024;                        //        64
    int*   done   = (int*)(gcnt + 64);                  //         1
    float* invdeg = (float*)(done + 1);                 //    50,000
    int*   slots  = (int*)(invdeg + 50000);             // 3,200,000
    ushort_t* Bt  = (ushort_t*)(slots + 3200000 + 3);   //    65,536 ushort (16B align)
    ushort_t* Bt2 = Bt + 65536;                         //     8,192 ushort
    ushort_t* ha  = Bt2 + 8192;                         // M_PAD*256 ushort
    float* p      = (float*)(ha + (size_t)M_PAD * 256); // M_PAD*16 float
    float* r      = p + (size_t)M_PAD * 16;             // M_PAD*16 float
    float* psum   = (float*)ha;                         // alias: ha dead after gemm1

    const int PB = 782;  // pool blocks
    prep_kernel<<<(N_NODES * 32 + 255) / 256, 256, 0, stream>>>(
        x, W1l, W1r, W2l, W2r, (uint_t*)ws, ha, Bt, Bt2);
    scatter_pad_kernel<<<(N_EDGES + 255) / 256, 256, 0, stream>>>(src, dst, cnt, slots);
    agg1_kernel<<<(N_NODES + 3) / 4, 256, 0, stream>>>(cnt, slots, ha, invdeg);
    gemm1_fused_kernel<<<M_PAD / 64, 256, 0, stream>>>(ha, Bt, Bt2, b1, p, r);
    agg2_kernel<<<(N_NODES + 3) / 4, 256, 0, stream>>>(p, cnt, slots, psum);
    pool_lsm_kernel<<<PB, 256, 0, stream>>>(psum, r, invdeg, b2, batch,
                                            gsum, gcnt, done, out, PB);
}